// Round 12
// baseline (275.623 us; speedup 1.0000x reference)
//
#include <hip/hip_runtime.h>
#include <hip/hip_bf16.h>

typedef __attribute__((ext_vector_type(8))) short short8;   // 8 bf16 (4 VGPRs)
typedef __attribute__((ext_vector_type(4))) float f32x4;    // MFMA C/D

#define L_SEQ 4096
#define DM    1024
#define DA    128
#define AZ    16     // attn z-split (block-level partials)

// ws byte offsets (16B-aligned)
#define OFF_QB   786432                       // after WTf (768 KB)
#define OFF_KF   1835008                      // after qb (1 MB)
#define OFF_VF   2883584                      // after kf (1 MB)
#define OFF_OA   4063232                      // vf + 1.125 MB
#define OFF_LA   (OFF_OA + (size_t)AZ * L_SEQ * DA * 4)   // OA 33.55 MB
#define OFF_CNT  (OFF_LA + (size_t)AZ * L_SEQ * 4)        // lA 256 KB

// fp32 -> bf16 round-to-nearest-even
__device__ __forceinline__ short f2bf(float f) {
    union { float f; unsigned u; } v; v.f = f;
    unsigned u = v.u;
    u += 0x7FFFu + ((u >> 16) & 1u);
    return (short)(u >> 16);
}

// async global->LDS, 16B per lane: dest = wave-uniform lds base + lane*16
typedef const __attribute__((address_space(1))) void g_void_t;
typedef __attribute__((address_space(3))) void l_void_t;
__device__ __forceinline__ void g2lds16(const void* g, void* l) {
    __builtin_amdgcn_global_load_lds((g_void_t*)g, (l_void_t*)l, 16, 0, 0);
}

// ---------------------------------------------------------------------------
// Kernel 0: W -> fragment-major bf16 + zero attn completion counters.
// WTf frag (m, kstep, nt, lane): elem j = W[kstep*32+quad*8+j][nt*16+l16].
// grid (32, 3), block 256.
// ---------------------------------------------------------------------------
__global__ __launch_bounds__(256) void prep_w_kernel(
    const float* __restrict__ Wq, const float* __restrict__ Wk,
    const float* __restrict__ Wv, short8* __restrict__ WTf,
    int* __restrict__ cnt)
{
    const int m = blockIdx.y, kidx = blockIdx.x;
    if (m == 0 && kidx == 0 && threadIdx.x < 64) cnt[threadIdx.x] = 0;

    const float* __restrict__ W = (m == 0) ? Wq : (m == 1) ? Wk : Wv;
    __shared__ __align__(16) float Ws[32 * 132];
    const int t = threadIdx.x;
#pragma unroll
    for (int i = 0; i < 4; i++) {
        const int u = i * 256 + t;
        const int kk = u >> 5, n4 = (u & 31) * 4;
        *(f32x4*)&Ws[kk * 132 + n4] = *(const f32x4*)&W[(size_t)(kidx * 32 + kk) * DA + n4];
    }
    __syncthreads();
#pragma unroll
    for (int i = 0; i < 2; i++) {
        const int u = i * 256 + t;
        const int nt = u >> 6, lane = u & 63, l16 = lane & 15, quad = lane >> 4;
        short8 fr;
#pragma unroll
        for (int j = 0; j < 8; j++)
            fr[j] = f2bf(Ws[(quad * 8 + j) * 132 + nt * 16 + l16]);
        WTf[((size_t)(m * 32 + kidx) * 8 + nt) * 64 + lane] = fr;
    }
}

// ---------------------------------------------------------------------------
// Kernel 1: fused QKV -> final attention-ready layouts (no partials).
// grid (256, 2), block 256.  by==0: q from x; by==1: k+v from z.
// Block: 16 rows x K=1024, BK=32 LDS dbuf (async staging).  Wave w owns
// cols [w*32, w*32+32).  Epilogue adds bias, writes qb row-major, kf/vf
// granule fragment layouts (vf nt==8 = ones column, row-sum trick).
// ---------------------------------------------------------------------------
__global__ __launch_bounds__(256, 2) void qkv_kernel(
    const float* __restrict__ x, const float* __restrict__ z,
    const char* __restrict__ WTraw,
    const float* __restrict__ bq, const float* __restrict__ bk,
    const float* __restrict__ bv,
    short* __restrict__ qb, short8* __restrict__ kf, short8* __restrict__ vf)
{
    __shared__ __align__(16) char smem[2][16384];

    const int t = threadIdx.x;
    const int w = t >> 6, lane = t & 63;
    const int l16 = lane & 15, quad = lane >> 4;
    const int isKV = blockIdx.y;
    const int row0 = blockIdx.x * 16;
    const int nbytes = isKV ? 16384 : 8192;

    const float* __restrict__ Am = isKV ? z : x;
    const float* ap = Am + (size_t)(row0 + l16) * DM + quad * 8;

    f32x4 acc1[2], acc2[2];
#pragma unroll
    for (int i = 0; i < 2; i++) {
        acc1[i] = (f32x4){0.f, 0.f, 0.f, 0.f};
        acc2[i] = (f32x4){0.f, 0.f, 0.f, 0.f};
    }

    auto stage = [&](int kidx, int b) {
        const char* base1 = WTraw + (size_t)(isKV * 32 + kidx) * 8192;
        const char* base2 = WTraw + (size_t)(64 + kidx) * 8192;
#pragma unroll
        for (int i = 0; i < 4; i++) {
            const int off = i * 4096 + w * 1024;
            if (off < nbytes) {
                const char* src = (off < 8192) ? (base1 + off) : (base2 + (off - 8192));
                g2lds16(src + lane * 16, &smem[b][off]);
            }
        }
    };

    f32x4 c0 = *(const f32x4*)ap,        c1 = *(const f32x4*)(ap + 4);
    f32x4 d0 = *(const f32x4*)(ap + 32), d1 = *(const f32x4*)(ap + 36);

    stage(0, 0);
    __syncthreads();

#pragma unroll 1
    for (int ks = 0; ks < 32; ks++) {
        const int b = ks & 1;
        if (ks + 1 < 32) stage(ks + 1, b ^ 1);

        const int kpf = (ks + 2 < 32) ? ks + 2 : ks;
        f32x4 e0 = *(const f32x4*)(ap + kpf * 32);
        f32x4 e1 = *(const f32x4*)(ap + kpf * 32 + 4);

        short8 afr;
#pragma unroll
        for (int j = 0; j < 4; j++) {
            afr[j]     = f2bf(c0[j]);
            afr[4 + j] = f2bf(c1[j]);
        }

#pragma unroll
        for (int ntl = 0; ntl < 2; ntl++) {
            short8 bfr = *(const short8*)&smem[b][((w * 2 + ntl) * 64 + lane) * 16];
            acc1[ntl] = __builtin_amdgcn_mfma_f32_16x16x32_bf16(afr, bfr, acc1[ntl], 0, 0, 0);
        }
        if (isKV) {
#pragma unroll
            for (int ntl = 0; ntl < 2; ntl++) {
                short8 bfr = *(const short8*)&smem[b][8192 + ((w * 2 + ntl) * 64 + lane) * 16];
                acc2[ntl] = __builtin_amdgcn_mfma_f32_16x16x32_bf16(afr, bfr, acc2[ntl], 0, 0, 0);
            }
        }
        __syncthreads();
        c0 = d0; c1 = d1; d0 = e0; d1 = e1;
    }

    // ---- epilogue.  C layout: row = quad*4 + r, col = w*32 + ntl*16 + l16 ----
    if (!isKV) {
#pragma unroll
        for (int ntl = 0; ntl < 2; ntl++) {
            const int col = w * 32 + ntl * 16 + l16;
            const float bb = bq[col];
#pragma unroll
            for (int r = 0; r < 4; r++)
                qb[(size_t)(row0 + quad * 4 + r) * DA + col] = f2bf(acc1[ntl][r] + bb);
        }
        return;
    }

    short* kT = (short*)&smem[0][0];
    short* vT = kT + 16 * 132;
#pragma unroll
    for (int ntl = 0; ntl < 2; ntl++) {
        const int col = w * 32 + ntl * 16 + l16;
        const float bbk = bk[col], bbv = bv[col];
#pragma unroll
        for (int r = 0; r < 4; r++) {
            const int rl = quad * 4 + r;
            kT[rl * 132 + col] = f2bf(acc1[ntl][r] + bbk);
            vT[rl * 132 + col] = f2bf(acc2[ntl][r] + bbv);
        }
    }
    asm volatile("" ::: "memory");
    __builtin_amdgcn_s_waitcnt(0xc07f);   // lgkmcnt(0) only
    asm volatile("" ::: "memory");

    const int kg = blockIdx.x >> 1, nth = blockIdx.x & 1;
    {
        short8 fr;
#pragma unroll
        for (int j = 0; j < 8; j++)
            fr[j] = kT[l16 * 132 + w * 32 + quad * 8 + j];
        kf[((size_t)(kg * 4 + w) * 2 + nth) * 64 + lane] = fr;
    }
    if ((quad >> 1) == nth) {
        const int lr0 = (quad - 2 * nth) * 8;
#pragma unroll
        for (int ntl = 0; ntl < 2; ntl++) {
            const int nt = w * 2 + ntl;
            short8 fr;
#pragma unroll
            for (int j = 0; j < 8; j++)
                fr[j] = vT[(lr0 + j) * 132 + nt * 16 + l16];
            vf[((size_t)kg * 9 + nt) * 64 + lane] = fr;
        }
        if (w == 3) {
            const short one = (short)0x3F80;
            short8 fr;
#pragma unroll
            for (int j = 0; j < 8; j++) fr[j] = (l16 == 0) ? one : (short)0;
            vf[((size_t)kg * 9 + 8) * 64 + lane] = fr;
        }
    }
}

// ---------------------------------------------------------------------------
// Kernel 2: flash attention (max-free softmax) + fused last-block merge.
// grid (64, AZ=16), block 256 (4 waves).  SINGLE K/V LDS buffer (22.6 KB)
// -> grid-capped 4 blocks/CU, 16 waves/CU: cross-block TLP hides the
// stage/drain latency (no intra-block double-buffer).  Wave owns 16 q-rows;
// all waves share each 32-z granule (8 granules per block).  The 16th
// finisher per bx sums partials in fixed zz order (deterministic) -> out.
// ---------------------------------------------------------------------------
__global__ __launch_bounds__(256) void attn_kernel(
    const short* __restrict__ qb, const char* __restrict__ kfg,
    const char* __restrict__ vfg, float* __restrict__ OA,
    float* __restrict__ lA, float* __restrict__ out, int* __restrict__ cnt)
{
    __shared__ __align__(16) char kv[17408];          // kf 8192 | vf 9216
    __shared__ __align__(16) short Ps[4][16 * 40];    // per-wave P round-trip
    __shared__ int lastFlag;

    const int t    = threadIdx.x;
    const int wave = t >> 6;
    const int lane = t & 63;
    const int l16  = lane & 15;
    const int quad = lane >> 4;
    const int qr0  = blockIdx.x * 64;
    const int g0   = blockIdx.y * 8;    // first z-granule (32 rows each)

    auto stage = [&](int g) {
        const char* kb_ = kfg + (size_t)(g0 + g) * 8192;
        const char* vb_ = vfg + (size_t)(g0 + g) * 9216;
#pragma unroll
        for (int i = 0; i < 5; i++) {
            const int off = i * 4096 + wave * 1024;
            if (off < 17408) {
                const char* src = (off < 8192) ? (kb_ + off) : (vb_ + (off - 8192));
                g2lds16(src + lane * 16, &kv[off]);
            }
        }
    };

    // q A-fragments direct from global (once)
    short8 af[4];
    const short* qrow = qb + (size_t)(qr0 + wave * 16 + l16) * DA + quad * 8;
#pragma unroll
    for (int ks = 0; ks < 4; ks++)
        af[ks] = *(const short8*)(qrow + ks * 32);

    f32x4 O[9];
#pragma unroll
    for (int i = 0; i < 9; i++) O[i] = (f32x4){0.f, 0.f, 0.f, 0.f};

    const float C = 0.08838834764831845f;   // 1/sqrt(128)
    short* P = &Ps[wave][0];

#pragma unroll 1
    for (int g = 0; g < 8; g++) {
        stage(g);
        __syncthreads();   // DMA drained (vmcnt 0) -> buffer full, waves synced

        const char* kb_ = &kv[0];
        const char* vb_ = &kv[8192];

        // ---- S = q @ k^T over this 32-z granule ----
        f32x4 s0[2];
#pragma unroll
        for (int nh = 0; nh < 2; nh++) s0[nh] = (f32x4){0.f, 0.f, 0.f, 0.f};
#pragma unroll
        for (int nh = 0; nh < 2; nh++)
#pragma unroll
            for (int ks = 0; ks < 4; ks++) {
                short8 bfr = *(const short8*)(kb_ + ((ks * 2 + nh) * 64 + lane) * 16);
                s0[nh] = __builtin_amdgcn_mfma_f32_16x16x32_bf16(af[ks], bfr, s0[nh], 0, 0, 0);
            }

        // ---- p = exp(s*C) -> P (wave-private LDS, A-operand layout) ----
#pragma unroll
        for (int nh = 0; nh < 2; nh++)
#pragma unroll
            for (int r = 0; r < 4; r++)
                P[(quad * 4 + r) * 40 + nh * 16 + l16] = f2bf(__expf(s0[nh][r] * C));
        asm volatile("" ::: "memory");
        __builtin_amdgcn_s_waitcnt(0xc07f);   // lgkmcnt(0) only
        asm volatile("" ::: "memory");

        // ---- O += P @ [V | 1] (K=32, single A-frag) ----
        short8 a2 = *(const short8*)&P[l16 * 40 + quad * 8];
#pragma unroll
        for (int nt = 0; nt < 9; nt++) {
            short8 b2 = *(const short8*)(vb_ + (nt * 64 + lane) * 16);
            O[nt] = __builtin_amdgcn_mfma_f32_16x16x32_bf16(a2, b2, O[nt], 0, 0, 0);
        }
        __syncthreads();   // all reads done before next stage overwrites
    }

    // ---- per-wave partial -> global (rows wave-exclusive) ----
    const int rw = qr0 + wave * 16;
    float* Ob = OA + (size_t)blockIdx.y * L_SEQ * DA;
#pragma unroll
    for (int nt = 0; nt < 8; nt++)
#pragma unroll
        for (int r = 0; r < 4; r++)
            Ob[(size_t)(rw + quad * 4 + r) * DA + nt * 16 + l16] = O[nt][r];
    if (l16 == 0) {
        float* lb = lA + (size_t)blockIdx.y * L_SEQ;
#pragma unroll
        for (int r = 0; r < 4; r++)
            lb[rw + quad * 4 + r] = O[8][r];
    }

    // ---- last-block merge (deterministic fixed-order sum) ----
    __threadfence();
    if (t == 0)
        lastFlag = (atomicAdd(&cnt[blockIdx.x], 1) == AZ - 1);
    __syncthreads();
    if (lastFlag) {
        __threadfence();
        const int row = qr0 + (t >> 2);
        const int cg = (t & 3) * 32;
        f32x4 a[8];
#pragma unroll
        for (int j = 0; j < 8; j++) a[j] = (f32x4){0.f, 0.f, 0.f, 0.f};
        float ls = 0.f;
        for (int zz = 0; zz < AZ; zz++) {
            const f32x4* p = (const f32x4*)&OA[((size_t)zz * L_SEQ + row) * DA + cg];
#pragma unroll
            for (int j = 0; j < 8; j++) a[j] = a[j] + p[j];
            ls += lA[(size_t)zz * L_SEQ + row];
        }
        const float inv = 1.f / ls;
        f32x4* dst = (f32x4*)&out[(size_t)row * DA + cg];
#pragma unroll
        for (int j = 0; j < 8; j++) dst[j] = a[j] * inv;
    }
}

// ---------------------------------------------------------------------------
extern "C" void kernel_launch(void* const* d_in, const int* in_sizes, int n_in,
                              void* d_out, int out_size, void* d_ws, size_t ws_size,
                              hipStream_t stream) {
    (void)in_sizes; (void)n_in; (void)out_size; (void)ws_size;
    const float* x  = (const float*)d_in[0];
    const float* z  = (const float*)d_in[1];
    const float* Wq = (const float*)d_in[2];
    const float* bq = (const float*)d_in[3];
    const float* Wk = (const float*)d_in[4];
    const float* bk = (const float*)d_in[5];
    const float* Wv = (const float*)d_in[6];
    const float* bv = (const float*)d_in[7];
    float* out = (float*)d_out;

    short8* WTf = (short8*)d_ws;
    short*  qb  = (short*)((char*)d_ws + OFF_QB);
    short8* kf  = (short8*)((char*)d_ws + OFF_KF);
    short8* vf  = (short8*)((char*)d_ws + OFF_VF);
    float*  OA  = (float*)((char*)d_ws + OFF_OA);     // AZ*L*DA fp32 = 33.55 MB
    float*  lA  = (float*)((char*)d_ws + OFF_LA);     // AZ*L fp32
    int*    cnt = (int*)((char*)d_ws + OFF_CNT);      // 64 ints

    prep_w_kernel<<<dim3(32, 3), 256, 0, stream>>>(Wq, Wk, Wv, WTf, cnt);
    qkv_kernel<<<dim3(256, 2), 256, 0, stream>>>(x, z, (const char*)WTf,
                                                 bq, bk, bv, qb, kf, vf);
    attn_kernel<<<dim3(64, AZ), 256, 0, stream>>>(qb, (const char*)kf,
                                                  (const char*)vf, OA, lA, out, cnt);
}

// Round 13
// 130.744 us; speedup vs baseline: 2.1081x; 2.1081x over previous
//
#include <hip/hip_runtime.h>
#include <hip/hip_bf16.h>

typedef __attribute__((ext_vector_type(8))) short short8;   // 8 bf16 (4 VGPRs)
typedef __attribute__((ext_vector_type(4))) float f32x4;    // MFMA C/D

#define L_SEQ 4096
#define DM    1024
#define DA    128
#define AZ    8      // attn z-split (block-level partials)

// ws byte offsets (16B-aligned)
#define OFF_QB  786432      // after WTf (768 KB)
#define OFF_KF  1835008     // after qb (1 MB)
#define OFF_VF  2883584     // after kf (1 MB)
#define OFF_OA  4063232     // after vf (1.125 MB): OA 16.78 MB, then lA 128 KB

// fp32 -> bf16 round-to-nearest-even
__device__ __forceinline__ short f2bf(float f) {
    union { float f; unsigned u; } v; v.f = f;
    unsigned u = v.u;
    u += 0x7FFFu + ((u >> 16) & 1u);
    return (short)(u >> 16);
}

// async global->LDS, 16B per lane: dest = wave-uniform lds base + lane*16
typedef const __attribute__((address_space(1))) void g_void_t;
typedef __attribute__((address_space(3))) void l_void_t;
__device__ __forceinline__ void g2lds16(const void* g, void* l) {
    __builtin_amdgcn_global_load_lds((g_void_t*)g, (l_void_t*)l, 16, 0, 0);
}

// ---------------------------------------------------------------------------
// Kernel 0: W -> fragment-major bf16.  WTf frag (m, kstep, nt, lane):
//   elem j = W[kstep*32 + quad*8 + j][nt*16 + l16].   grid (32,3), block 256.
// ---------------------------------------------------------------------------
__global__ __launch_bounds__(256) void prep_w_kernel(
    const float* __restrict__ Wq, const float* __restrict__ Wk,
    const float* __restrict__ Wv, short8* __restrict__ WTf)
{
    const int m = blockIdx.y, kidx = blockIdx.x;
    const float* __restrict__ W = (m == 0) ? Wq : (m == 1) ? Wk : Wv;
    __shared__ __align__(16) float Ws[32 * 132];
    const int t = threadIdx.x;
#pragma unroll
    for (int i = 0; i < 4; i++) {
        const int u = i * 256 + t;
        const int kk = u >> 5, n4 = (u & 31) * 4;
        *(f32x4*)&Ws[kk * 132 + n4] = *(const f32x4*)&W[(size_t)(kidx * 32 + kk) * DA + n4];
    }
    __syncthreads();
#pragma unroll
    for (int i = 0; i < 2; i++) {
        const int u = i * 256 + t;
        const int nt = u >> 6, lane = u & 63, l16 = lane & 15, quad = lane >> 4;
        short8 fr;
#pragma unroll
        for (int j = 0; j < 8; j++)
            fr[j] = f2bf(Ws[(quad * 8 + j) * 132 + nt * 16 + l16]);
        WTf[((size_t)(m * 32 + kidx) * 8 + nt) * 64 + lane] = fr;
    }
}

// ---------------------------------------------------------------------------
// Kernel 1: fused QKV.  grid (128, 2), block 256.  by==0: q from x; by==1:
// k AND v from z (z read once).  Block owns 32 rows x full K=1024, BK=64
// (16 dbuf iterations).  Wave -> (mtile = w>>1, nhalf = w&1).  Epilogue
// writes FINAL outputs (bias added): qb row-major; k/v relaid to granule
// fragment layouts via LDS transpose (reusing staging buffer).
//   kf granule kg=z>>5: frag(kg,ks,nth,lane) elem j = k[kg*32+nth*16+l16][ks*32+quad*8+j]
//   vf granule vg=z>>5: frag(vg,nt,lane)     elem j = v[vg*32+quad*8+j][nt*16+l16]
//     nt==8 = ones column (row-sum trick).
// ---------------------------------------------------------------------------
__global__ __launch_bounds__(256, 1) void qkv_kernel(
    const float* __restrict__ x, const float* __restrict__ z,
    const char* __restrict__ WTraw,
    const float* __restrict__ bq, const float* __restrict__ bk,
    const float* __restrict__ bv,
    short* __restrict__ qb, short8* __restrict__ kf, short8* __restrict__ vf)
{
    __shared__ __align__(16) char smem[2][32768];

    const int t = threadIdx.x;
    const int wave = t >> 6, lane = t & 63;
    const int l16 = lane & 15, quad = lane >> 4;
    const int mtile = wave >> 1, nhalf = wave & 1;
    const int isKV = blockIdx.y;
    const int m1 = isKV ? 1 : 0;
    const int row0 = blockIdx.x * 32;
    const int nbytes = isKV ? 32768 : 16384;

    const float* __restrict__ Am = isKV ? z : x;
    const float* ap = Am + (size_t)(row0 + mtile * 16 + l16) * DM + quad * 8;

    f32x4 acc1[4], acc2[4];
#pragma unroll
    for (int i = 0; i < 4; i++) {
        acc1[i] = (f32x4){0.f, 0.f, 0.f, 0.f};
        acc2[i] = (f32x4){0.f, 0.f, 0.f, 0.f};
    }

    // stage W frags for BK=64 iteration it2 into smem[b]:
    //   [m1 kstep even 8K][m1 kstep odd 8K][(kv) Wv even 8K][Wv odd 8K]
    auto stage = [&](int it2, int b) {
        const char* base1 = WTraw + (size_t)(m1 * 32 + it2 * 2) * 8192;
        const char* base2 = WTraw + (size_t)(2 * 32 + it2 * 2) * 8192;
#pragma unroll
        for (int i = 0; i < 8; i++) {
            const int off = i * 4096 + wave * 1024;
            if (off < nbytes) {
                const char* src = (off < 16384) ? (base1 + off) : (base2 + (off - 16384));
                g2lds16(src + lane * 16, &smem[b][off]);
            }
        }
    };

    // A pipeline: 4 f32x4 per iteration (two 32-k substeps), prefetch depth 2
    f32x4 cur[4], nxt[4];
#pragma unroll
    for (int j = 0; j < 2; j++) {
        cur[j * 2]     = *(const f32x4*)(ap + j * 32);
        cur[j * 2 + 1] = *(const f32x4*)(ap + j * 32 + 4);
        nxt[j * 2]     = *(const f32x4*)(ap + 64 + j * 32);
        nxt[j * 2 + 1] = *(const f32x4*)(ap + 64 + j * 32 + 4);
    }

    stage(0, 0);
    __syncthreads();

#pragma unroll 1
    for (int it = 0; it < 16; it++) {
        const int b = it & 1;
        if (it + 1 < 16) stage(it + 1, b ^ 1);

        const int ipf = (it + 2 < 16) ? it + 2 : it;
        f32x4 fut[4];
#pragma unroll
        for (int j = 0; j < 2; j++) {
            fut[j * 2]     = *(const f32x4*)(ap + ipf * 64 + j * 32);
            fut[j * 2 + 1] = *(const f32x4*)(ap + ipf * 64 + j * 32 + 4);
        }

#pragma unroll
        for (int ss = 0; ss < 2; ss++) {
            short8 afr;
#pragma unroll
            for (int j = 0; j < 4; j++) {
                afr[j]     = f2bf(cur[ss * 2][j]);
                afr[4 + j] = f2bf(cur[ss * 2 + 1][j]);
            }
#pragma unroll
            for (int ntl = 0; ntl < 4; ntl++) {
                short8 bfr = *(const short8*)&smem[b][ss * 8192 + ((nhalf * 4 + ntl) * 64 + lane) * 16];
                acc1[ntl] = __builtin_amdgcn_mfma_f32_16x16x32_bf16(afr, bfr, acc1[ntl], 0, 0, 0);
            }
            if (isKV) {
#pragma unroll
                for (int ntl = 0; ntl < 4; ntl++) {
                    short8 bfr = *(const short8*)&smem[b][16384 + ss * 8192 + ((nhalf * 4 + ntl) * 64 + lane) * 16];
                    acc2[ntl] = __builtin_amdgcn_mfma_f32_16x16x32_bf16(afr, bfr, acc2[ntl], 0, 0, 0);
                }
            }
        }
        __syncthreads();
#pragma unroll
        for (int j = 0; j < 4; j++) { cur[j] = nxt[j]; nxt[j] = fut[j]; }
    }

    // ---- epilogue.  C layout: row = mtile*16 + quad*4 + r, col = nhalf*64 + ntl*16 + l16
    if (!isKV) {
#pragma unroll
        for (int ntl = 0; ntl < 4; ntl++) {
            const int col = nhalf * 64 + ntl * 16 + l16;
            const float bb = bq[col];
#pragma unroll
            for (int r = 0; r < 4; r++)
                qb[(size_t)(row0 + mtile * 16 + quad * 4 + r) * DA + col] =
                    f2bf(acc1[ntl][r] + bb);
        }
        return;
    }

    // k/v: C-frags -> LDS tiles [32][132] (k at smem 0, v at smem +16384)
    short* kT = (short*)&smem[0][0];
    short* vT = (short*)&smem[0][16384];
#pragma unroll
    for (int ntl = 0; ntl < 4; ntl++) {
        const int col = nhalf * 64 + ntl * 16 + l16;
        const float bbk = bk[col], bbv = bv[col];
#pragma unroll
        for (int r = 0; r < 4; r++) {
            const int rl = mtile * 16 + quad * 4 + r;
            kT[rl * 132 + col] = f2bf(acc1[ntl][r] + bbk);
            vT[rl * 132 + col] = f2bf(acc2[ntl][r] + bbv);
        }
    }
    __syncthreads();

    const int kg = blockIdx.x;   // this block's 32 rows = one granule
    // kf: 512 frags
#pragma unroll
    for (int i = 0; i < 2; i++) {
        const int f = i * 256 + t;
        const int ks = f >> 7, nth = (f >> 6) & 1, ln = f & 63;
        const int lf = ln & 15, qf = ln >> 4;
        short8 fr;
#pragma unroll
        for (int j = 0; j < 8; j++)
            fr[j] = kT[(nth * 16 + lf) * 132 + ks * 32 + qf * 8 + j];
        kf[((size_t)(kg * 4 + ks) * 2 + nth) * 64 + ln] = fr;
    }
    // vf: 576 frags (incl. ones tile nt==8)
#pragma unroll
    for (int i = 0; i < 3; i++) {
        const int f = i * 256 + t;
        if (f < 576) {
            const int nt = f >> 6, ln = f & 63;
            const int lf = ln & 15, qf = ln >> 4;
            short8 fr;
            if (nt < 8) {
#pragma unroll
                for (int j = 0; j < 8; j++)
                    fr[j] = vT[(qf * 8 + j) * 132 + nt * 16 + lf];
            } else {
                const short one = (short)0x3F80;
#pragma unroll
                for (int j = 0; j < 8; j++) fr[j] = (lf == 0) ? one : (short)0;
            }
            vf[((size_t)kg * 9 + nt) * 64 + ln] = fr;
        }
    }
}

// ---------------------------------------------------------------------------
// Kernel 2: flash attention (max-free softmax), K/V via LDS double-buffer.
// grid (64, AZ), block 256 (4 waves), 2 blocks/CU.  Wave owns 16 q-rows;
// all waves share each 32-z-row granule (16 granules per block).
// ---------------------------------------------------------------------------
__global__ __launch_bounds__(256, 2) void attn_kernel(
    const short* __restrict__ qb, const char* __restrict__ kfg,
    const char* __restrict__ vfg, float* __restrict__ OA,
    float* __restrict__ lA)
{
    __shared__ __align__(16) char kv[2][17408];       // [buf][kf 8192 | vf 9216]
    __shared__ __align__(16) short Ps[4][16 * 40];    // per-wave P round-trip

    const int t    = threadIdx.x;
    const int wave = t >> 6;
    const int lane = t & 63;
    const int l16  = lane & 15;
    const int quad = lane >> 4;
    const int qr0  = blockIdx.x * 64;
    const int g0   = blockIdx.y * 16;   // first z-granule (32 rows each)

    auto stage = [&](int g, int b) {
        const char* kb_ = kfg + (size_t)(g0 + g) * 8192;
        const char* vb_ = vfg + (size_t)(g0 + g) * 9216;
#pragma unroll
        for (int i = 0; i < 5; i++) {
            const int off = i * 4096 + wave * 1024;
            if (off < 17408) {
                const char* src = (off < 8192) ? (kb_ + off) : (vb_ + (off - 8192));
                g2lds16(src + lane * 16, &kv[b][off]);
            }
        }
    };

    stage(0, 0);

    // q A-fragments direct from global (once; overlaps staging)
    short8 af[4];
    const short* qrow = qb + (size_t)(qr0 + wave * 16 + l16) * DA + quad * 8;
#pragma unroll
    for (int ks = 0; ks < 4; ks++)
        af[ks] = *(const short8*)(qrow + ks * 32);

    f32x4 O[9];
#pragma unroll
    for (int i = 0; i < 9; i++) O[i] = (f32x4){0.f, 0.f, 0.f, 0.f};

    const float C = 0.08838834764831845f;   // 1/sqrt(128)
    short* P = &Ps[wave][0];

    __syncthreads();   // buf0 ready

#pragma unroll 1
    for (int g = 0; g < 16; g++) {
        const int b = g & 1;
        if (g + 1 < 16) stage(g + 1, b ^ 1);   // async; drains at end-of-iter barrier

        const char* kb_ = &kv[b][0];
        const char* vb_ = &kv[b][8192];

        // ---- S = q @ k^T over this 32-z granule ----
        f32x4 s0[2];
#pragma unroll
        for (int nh = 0; nh < 2; nh++) s0[nh] = (f32x4){0.f, 0.f, 0.f, 0.f};
#pragma unroll
        for (int nh = 0; nh < 2; nh++)
#pragma unroll
            for (int ks = 0; ks < 4; ks++) {
                short8 bfr = *(const short8*)(kb_ + ((ks * 2 + nh) * 64 + lane) * 16);
                s0[nh] = __builtin_amdgcn_mfma_f32_16x16x32_bf16(af[ks], bfr, s0[nh], 0, 0, 0);
            }

        // ---- p = exp(s*C) -> P (wave-private LDS, A-operand layout) ----
#pragma unroll
        for (int nh = 0; nh < 2; nh++)
#pragma unroll
            for (int r = 0; r < 4; r++)
                P[(quad * 4 + r) * 40 + nh * 16 + l16] = f2bf(__expf(s0[nh][r] * C));
        // wave-local DS RAW: wait LDS writes only (keep async prefetch in flight)
        asm volatile("" ::: "memory");
        __builtin_amdgcn_s_waitcnt(0xc07f);   // lgkmcnt(0) only
        asm volatile("" ::: "memory");

        // ---- O += P @ [V | 1] (K=32, single A-frag) ----
        short8 a2 = *(const short8*)&P[l16 * 40 + quad * 8];
#pragma unroll
        for (int nt = 0; nt < 9; nt++) {
            short8 b2 = *(const short8*)(vb_ + (nt * 64 + lane) * 16);
            O[nt] = __builtin_amdgcn_mfma_f32_16x16x32_bf16(a2, b2, O[nt], 0, 0, 0);
        }
        __syncthreads();   // staging for g+1 drained; all waves done with buf b
    }

    // ---- per-wave partial -> global (rows wave-exclusive) ----
    const int rw = qr0 + wave * 16;
    float* Ob = OA + (size_t)blockIdx.y * L_SEQ * DA;
#pragma unroll
    for (int nt = 0; nt < 8; nt++)
#pragma unroll
        for (int r = 0; r < 4; r++)
            Ob[(size_t)(rw + quad * 4 + r) * DA + nt * 16 + l16] = O[nt][r];
    if (l16 == 0) {
        float* lb = lA + (size_t)blockIdx.y * L_SEQ;
#pragma unroll
        for (int r = 0; r < 4; r++)
            lb[rw + quad * 4 + r] = O[8][r];
    }
}

// ---------------------------------------------------------------------------
// Kernel 3: merge AZ partials: out = sum(OA) / sum(lA).  grid 256, block 256.
// ---------------------------------------------------------------------------
__global__ __launch_bounds__(256) void merge_kernel(
    const float* __restrict__ OA, const float* __restrict__ lA,
    float* __restrict__ out)
{
    const int t = threadIdx.x;
    const int row = blockIdx.x * 16 + (t >> 4);
    const int cg = (t & 15) * 8;

    f32x4 a0 = (f32x4){0.f, 0.f, 0.f, 0.f};
    f32x4 a1 = (f32x4){0.f, 0.f, 0.f, 0.f};
    float lsum = 0.f;
#pragma unroll
    for (int zz = 0; zz < AZ; zz++) {
        const float* p = &OA[((size_t)zz * L_SEQ + row) * DA + cg];
        a0 = a0 + *(const f32x4*)p;
        a1 = a1 + *(const f32x4*)(p + 4);
        lsum += lA[(size_t)zz * L_SEQ + row];
    }
    const float inv = 1.f / lsum;
    f32x4* dst = (f32x4*)&out[(size_t)row * DA + cg];
    dst[0] = a0 * inv;
    dst[1] = a1 * inv;
}

// ---------------------------------------------------------------------------
extern "C" void kernel_launch(void* const* d_in, const int* in_sizes, int n_in,
                              void* d_out, int out_size, void* d_ws, size_t ws_size,
                              hipStream_t stream) {
    (void)in_sizes; (void)n_in; (void)out_size; (void)ws_size;
    const float* x  = (const float*)d_in[0];
    const float* z  = (const float*)d_in[1];
    const float* Wq = (const float*)d_in[2];
    const float* bq = (const float*)d_in[3];
    const float* Wk = (const float*)d_in[4];
    const float* bk = (const float*)d_in[5];
    const float* Wv = (const float*)d_in[6];
    const float* bv = (const float*)d_in[7];
    float* out = (float*)d_out;

    short8* WTf = (short8*)d_ws;
    short*  qb  = (short*)((char*)d_ws + OFF_QB);
    short8* kf  = (short8*)((char*)d_ws + OFF_KF);
    short8* vf  = (short8*)((char*)d_ws + OFF_VF);
    float*  OA  = (float*)((char*)d_ws + OFF_OA);            // AZ*L*DA fp32
    float*  lA  = (float*)((char*)d_ws + OFF_OA + (size_t)AZ * L_SEQ * DA * 4);

    prep_w_kernel<<<dim3(32, 3), 256, 0, stream>>>(Wq, Wk, Wv, WTf);
    qkv_kernel<<<dim3(128, 2), 256, 0, stream>>>(x, z, (const char*)WTf,
                                                 bq, bk, bv, qb, kf, vf);
    attn_kernel<<<dim3(64, AZ), 256, 0, stream>>>(qb, (const char*)kf,
                                                  (const char*)vf, OA, lA);
    merge_kernel<<<256, 256, 0, stream>>>(OA, lA, out);
}